// Round 6
// baseline (887.795 us; speedup 1.0000x reference)
//
#include <hip/hip_runtime.h>
#include <hip/hip_bf16.h>

// ---------------- constants ----------------
#define BQ 2
#define NQ 1024
#define CM 256
#define HEADS 8
#define DH 32
#define FFD 2048
#define TV 16
#define HV 128
#define WV 128
#define TD 8
#define HD 16
#define WD 16
#define LS 2048              // TD*HD*WD samples per group
#define NG 16                // B * HEADS groups
#define MROWS 2048           // B*NQ token rows

// ---------------- generic f32 NT GEMM: C = A(MxK) @ W(NxK)^T (+bias)(+res)(+relu) ----------------
template <bool RELU>
__global__ __launch_bounds__(256) void gemm_nt(const float* __restrict__ A,
                                               const float* __restrict__ Wt,
                                               const float* __restrict__ bias,
                                               const float* __restrict__ res,
                                               float* __restrict__ C,
                                               int M, int N, int K) {
  __shared__ float As[16 * 68];
  __shared__ float Ws[16 * 68];
  const int tm = threadIdx.x & 15;
  const int tn = threadIdx.x >> 4;
  const int m0 = blockIdx.x * 64, n0 = blockIdx.y * 64;
  const int lr = threadIdx.x >> 2;
  const int lk = (threadIdx.x & 3) * 4;
  float acc[4][4] = {};
  for (int k0 = 0; k0 < K; k0 += 16) {
    float4 a4 = *(const float4*)(A + (size_t)(m0 + lr) * K + k0 + lk);
    float4 w4 = *(const float4*)(Wt + (size_t)(n0 + lr) * K + k0 + lk);
    As[(lk + 0) * 68 + lr] = a4.x;
    As[(lk + 1) * 68 + lr] = a4.y;
    As[(lk + 2) * 68 + lr] = a4.z;
    As[(lk + 3) * 68 + lr] = a4.w;
    Ws[(lk + 0) * 68 + lr] = w4.x;
    Ws[(lk + 1) * 68 + lr] = w4.y;
    Ws[(lk + 2) * 68 + lr] = w4.z;
    Ws[(lk + 3) * 68 + lr] = w4.w;
    __syncthreads();
#pragma unroll
    for (int k = 0; k < 16; ++k) {
      float4 av = *(const float4*)&As[k * 68 + tm * 4];
      float4 wv = *(const float4*)&Ws[k * 68 + tn * 4];
      float a[4] = {av.x, av.y, av.z, av.w};
      float w[4] = {wv.x, wv.y, wv.z, wv.w};
#pragma unroll
      for (int i = 0; i < 4; ++i)
#pragma unroll
        for (int j = 0; j < 4; ++j) acc[i][j] += a[i] * w[j];
    }
    __syncthreads();
  }
#pragma unroll
  for (int i = 0; i < 4; ++i) {
    const int row = m0 + tm * 4 + i;
    const int col = n0 + tn * 4;
    float4 bv = bias ? *(const float4*)(bias + col) : make_float4(0.f, 0.f, 0.f, 0.f);
    float4 rv = res ? *(const float4*)(res + (size_t)row * N + col) : make_float4(0.f, 0.f, 0.f, 0.f);
    float4 o;
    o.x = acc[i][0] + bv.x + rv.x;
    o.y = acc[i][1] + bv.y + rv.y;
    o.z = acc[i][2] + bv.z + rv.z;
    o.w = acc[i][3] + bv.w + rv.w;
    if (RELU) {
      o.x = fmaxf(o.x, 0.f); o.y = fmaxf(o.y, 0.f);
      o.z = fmaxf(o.z, 0.f); o.w = fmaxf(o.w, 0.f);
    }
    *(float4*)(C + (size_t)row * N + col) = o;
  }
}

// ---------------- self-attention: single-pass flash (scores provably tiny -> no max) ----------------
#define SKC 64
#define SNC (NQ / SKC)
__global__ __launch_bounds__(256) void sa_flash_kernel(const float* __restrict__ qkv,
                                                       float* __restrict__ o) {
  __shared__ float Qs[16][36];
  __shared__ float Ks[SKC][36];
  __shared__ float Vs[SKC][36];
  __shared__ float Ps[16][68];
  __shared__ float Ored[8 * 16 * 32];

  const int swz = (blockIdx.x & 7) * 128 + (blockIdx.x >> 3);
  const int bh = swz >> 6, qt = swz & 63;
  const int n0 = qt * 16;
  const int b = bh >> 3, h = bh & 7;
  const int tid = threadIdx.x;
  const int lane = tid & 63, wave = tid >> 6;

  const float* rowbase = qkv + (size_t)b * NQ * 768 + h * DH;

  if (tid < 128) {
    const int r = tid >> 3, c4 = (tid & 7) * 4;
    *(float4*)&Qs[r][c4] = *(const float4*)(rowbase + (size_t)(n0 + r) * 768 + c4);
  }
  __syncthreads();

  const int dslot = (tid >> 3) & 7;
  const int kg = tid & 7;
  float ssum[4] = {0.f, 0.f, 0.f, 0.f};
  float o0[4] = {}, o1[4] = {}, o2[4] = {}, o3[4] = {};

#pragma unroll 1
  for (int c = 0; c < SNC; ++c) {
    {
      const int r0 = tid >> 3, c40 = (tid & 7) * 4;
      const int r1 = r0 + 32;
      *(float4*)&Ks[r0][c40] =
          *(const float4*)(rowbase + (size_t)(c * SKC + r0) * 768 + 256 + c40);
      *(float4*)&Ks[r1][c40] =
          *(const float4*)(rowbase + (size_t)(c * SKC + r1) * 768 + 256 + c40);
      *(float4*)&Vs[r0][c40] =
          *(const float4*)(rowbase + (size_t)(c * SKC + r0) * 768 + 512 + c40);
      *(float4*)&Vs[r1][c40] =
          *(const float4*)(rowbase + (size_t)(c * SKC + r1) * 768 + 512 + c40);
    }
    __syncthreads();
    float4 kr[8];
#pragma unroll
    for (int d4 = 0; d4 < 8; ++d4) kr[d4] = *(const float4*)&Ks[lane][d4 * 4];
#pragma unroll
    for (int qi = 0; qi < 4; ++qi) {
      const int q = wave * 4 + qi;
      float s = 0.f;
#pragma unroll
      for (int d4 = 0; d4 < 8; ++d4) {
        float4 q4 = *(const float4*)&Qs[q][d4 * 4];
        s += q4.x * kr[d4].x + q4.y * kr[d4].y + q4.z * kr[d4].z + q4.w * kr[d4].w;
      }
      const float e = __expf(s * 0.17677669529663687f);
      ssum[qi] += e;
      Ps[q][lane] = e;
    }
    // P rows of wave w written & read by the same wave -> no block barrier needed
#pragma unroll
    for (int j = 0; j < 8; ++j) {
      const int kk = kg * 8 + j;
      float4 v4 = *(const float4*)&Vs[kk][dslot * 4];
      const float p0 = Ps[wave * 4 + 0][kk];
      const float p1 = Ps[wave * 4 + 1][kk];
      const float p2 = Ps[wave * 4 + 2][kk];
      const float p3 = Ps[wave * 4 + 3][kk];
      o0[0] += p0 * v4.x; o0[1] += p0 * v4.y; o0[2] += p0 * v4.z; o0[3] += p0 * v4.w;
      o1[0] += p1 * v4.x; o1[1] += p1 * v4.y; o1[2] += p1 * v4.z; o1[3] += p1 * v4.w;
      o2[0] += p2 * v4.x; o2[1] += p2 * v4.y; o2[2] += p2 * v4.z; o2[3] += p2 * v4.w;
      o3[0] += p3 * v4.x; o3[1] += p3 * v4.y; o3[2] += p3 * v4.z; o3[3] += p3 * v4.w;
    }
    __syncthreads();
  }

  float inv[4];
#pragma unroll
  for (int qi = 0; qi < 4; ++qi) {
    float ss = ssum[qi];
#pragma unroll
    for (int off = 32; off > 0; off >>= 1) ss += __shfl_xor(ss, off, 64);
    inv[qi] = 1.f / ss;
  }

#pragma unroll
  for (int j = 0; j < 4; ++j) {
    Ored[kg * (16 * 32) + (wave * 4 + 0) * 32 + dslot * 4 + j] = o0[j] * inv[0];
    Ored[kg * (16 * 32) + (wave * 4 + 1) * 32 + dslot * 4 + j] = o1[j] * inv[1];
    Ored[kg * (16 * 32) + (wave * 4 + 2) * 32 + dslot * 4 + j] = o2[j] * inv[2];
    Ored[kg * (16 * 32) + (wave * 4 + 3) * 32 + dslot * 4 + j] = o3[j] * inv[3];
  }
  __syncthreads();
#pragma unroll
  for (int i = 0; i < 2; ++i) {
    const int idx = tid * 2 + i;
    const int q = idx >> 5, d = idx & 31;
    float s = 0.f;
#pragma unroll
    for (int k = 0; k < 8; ++k) s += Ored[k * (16 * 32) + q * 32 + d];
    o[((size_t)(b * NQ + n0 + q)) * CM + h * DH + d] = s;
  }
}

// ---------------- layer norm (one wave per 256-dim row), f32 out ----------------
__global__ __launch_bounds__(256) void ln_kernel(const float* __restrict__ in,
                                                 const float* __restrict__ w,
                                                 const float* __restrict__ b,
                                                 float* __restrict__ out) {
  const int wv = threadIdx.x >> 6, lane = threadIdx.x & 63;
  const int row = blockIdx.x * 4 + wv;
  float4 v = ((const float4*)(in + (size_t)row * CM))[lane];
  float s = v.x + v.y + v.z + v.w;
#pragma unroll
  for (int off = 32; off > 0; off >>= 1) s += __shfl_xor(s, off, 64);
  const float mu = s * (1.f / 256.f);
  float dx = v.x - mu, dy = v.y - mu, dz = v.z - mu, dw = v.w - mu;
  float q = dx * dx + dy * dy + dz * dz + dw * dw;
#pragma unroll
  for (int off = 32; off > 0; off >>= 1) q += __shfl_xor(q, off, 64);
  const float r = rsqrtf(q * (1.f / 256.f) + 1e-5f);
  float4 wv4 = ((const float4*)w)[lane];
  float4 bv4 = ((const float4*)b)[lane];
  float4 o;
  o.x = dx * r * wv4.x + bv4.x;
  o.y = dy * r * wv4.y + bv4.y;
  o.z = dz * r * wv4.z + bv4.z;
  o.w = dw * r * wv4.w + bv4.w;
  ((float4*)(out + (size_t)row * CM))[lane] = o;
}

// ---------------- depthwise strided conv + bias + gelu(tanh) ----------------
// bid remapped so all 8 zo-blocks of one (bg,c) land on the SAME XCD, 8 dispatch
// slots apart -> overlapping z-planes hit that XCD's L2 instead of HBM.
__global__ __launch_bounds__(256) void conv_off_kernel(const float* __restrict__ gt,
                                                       const float* __restrict__ w1,
                                                       const float* __restrict__ b1,
                                                       float* __restrict__ off1) {
  const int bid = blockIdx.x;
  const int cid = ((bid >> 6) << 3) | (bid & 7);  // 0..511, cid%8 == bid%8
  const int zo = (bid >> 3) & 7;
  const int c = cid & 31, bg = cid >> 5;
  const int xo = threadIdx.x & 15, yo = threadIdx.x >> 4;
  __shared__ float wsm[400];
  for (int i = threadIdx.x; i < 400; i += 256) wsm[i] = w1[c * 400 + i];
  __syncthreads();
  const float* xp = gt + (size_t)(bg * 32 + c) * (TV * HV * WV);
  float acc = 0.f;
  for (int kz = 0; kz < 4; ++kz) {
    const int z = zo * 2 - 1 + kz;
    if ((unsigned)z >= (unsigned)TV) continue;
    const float* xz = xp + (size_t)z * (HV * WV);
    for (int ky = 0; ky < 10; ++ky) {
      const int y = yo * 8 - 1 + ky;
      if ((unsigned)y >= (unsigned)HV) continue;
      const float* xy = xz + y * WV;
      const float* wr = wsm + kz * 100 + ky * 10;
      const int xbase = xo * 8 - 1;
#pragma unroll
      for (int kx = 0; kx < 10; ++kx) {
        const int x = xbase + kx;
        if ((unsigned)x < (unsigned)WV) acc += wr[kx] * xy[x];
      }
    }
  }
  acc += b1[c];
  const float u = 0.7978845608028654f * (acc + 0.044715f * acc * acc * acc);
  const float gv = 0.5f * acc * (1.f + tanhf(u));
  off1[((size_t)(bg * 32 + c) * TD + zo) * (HD * WD) + yo * WD + xo] = gv;
}

// ---------------- offset projection + tanh*scale + pixel coords ----------------
__global__ __launch_bounds__(256) void offproj_kernel(const float* __restrict__ off1,
                                                      const float* __restrict__ w2,
                                                      float* __restrict__ pc) {
  const int gid = blockIdx.x * 256 + threadIdx.x;  // 16*2048
  const int bg = gid >> 11, sp = gid & 2047;
  const float* base = off1 + (size_t)bg * 32 * LS + sp;
  float o0 = 0.f, o1 = 0.f, o2 = 0.f;
#pragma unroll
  for (int c = 0; c < 32; ++c) {
    const float v = base[(size_t)c * LS];
    o0 += w2[c] * v;
    o1 += w2[32 + c] * v;
    o2 += w2[64 + c] * v;
  }
  const int gz = sp >> 8, gy = (sp >> 4) & 15, gx = sp & 15;
  const float oz = tanhf(o0) * 2.f;
  const float oy = tanhf(o1) * 8.f;
  const float ox = tanhf(o2) * 8.f;
  float* p = pc + (size_t)gid * 3;
  p[0] = ((float)gz + oz) * (16.f / 7.f) - 0.5f;
  p[1] = ((float)gy + oy) * (128.f / 15.f) - 0.5f;
  p[2] = ((float)gx + ox) * (128.f / 15.f) - 0.5f;
}

// ---------------- trilinear grid sample + per-group k/v projection ----------------
__global__ __launch_bounds__(256) void gsample_kernel(const float* __restrict__ gt,
                                                      const float* __restrict__ pc,
                                                      const float* __restrict__ kw,
                                                      const float* __restrict__ vw,
                                                      float* __restrict__ kbuf,
                                                      float* __restrict__ vbuf) {
  __shared__ float kvv[8][33];
  __shared__ float kws[32][33], vws[32][33];
  const int bg = blockIdx.x >> 8, l0 = (blockIdx.x & 255) * 8;
  const int g = bg & 7;
  const int s = threadIdx.x >> 5, c = threadIdx.x & 31;
  for (int i = threadIdx.x; i < 1024; i += 256) {
    kws[i >> 5][i & 31] = kw[g * 1024 + i];
    vws[i >> 5][i & 31] = vw[g * 1024 + i];
  }
  const int l = l0 + s;
  const float* p = pc + ((size_t)bg * LS + l) * 3;
  const float pz = p[0], py = p[1], px = p[2];
  const float zf = floorf(pz), yf = floorf(py), xf = floorf(px);
  const int z0 = (int)zf, y0 = (int)yf, x0 = (int)xf;
  const float fz = pz - zf, fy = py - yf, fx = px - xf;
  const float* vp = gt + (size_t)(bg * 32 + c) * (TV * HV * WV);
  float acc = 0.f;
#pragma unroll
  for (int dz = 0; dz < 2; ++dz) {
    const int z = z0 + dz;
    if ((unsigned)z >= (unsigned)TV) continue;
    const float wz = dz ? fz : 1.f - fz;
#pragma unroll
    for (int dy = 0; dy < 2; ++dy) {
      const int y = y0 + dy;
      if ((unsigned)y >= (unsigned)HV) continue;
      const float wzy = wz * (dy ? fy : 1.f - fy);
#pragma unroll
      for (int dx = 0; dx < 2; ++dx) {
        const int x = x0 + dx;
        if ((unsigned)x >= (unsigned)WV) continue;
        acc += wzy * (dx ? fx : 1.f - fx) * vp[((size_t)z * HV + y) * WV + x];
      }
    }
  }
  kvv[s][c] = acc;
  __syncthreads();
  float ka = 0.f, va = 0.f;
#pragma unroll
  for (int f = 0; f < 32; ++f) {
    const float kv = kvv[s][f];
    ka += kws[c][f] * kv;
    va += vws[c][f] * kv;
  }
  kbuf[((size_t)bg * LS + l) * 32 + c] = ka;
  vbuf[((size_t)bg * LS + l) * 32 + c] = va;
}

// ---------------- deformable attention: two-pass, no-max softmax ----------------
#define DQT 16
#define DKC 64
#define DNC (LS / DKC)
__global__ __launch_bounds__(256) void dattn_kernel(const float* __restrict__ qb,
                                                    const float* __restrict__ kbuf,
                                                    const float* __restrict__ vbuf,
                                                    float* __restrict__ da_o,
                                                    float* __restrict__ attn_out) {
  __shared__ float Qs[DQT][36];
  __shared__ float Ks[DKC][36];
  __shared__ float Vs[DKC][36];
  __shared__ float Ps[DQT][68];
  __shared__ float Ored[8 * DQT * 32];

  const int swz = (blockIdx.x & 7) * 128 + (blockIdx.x >> 3);
  const int bg = swz >> 6, qt = swz & 63;
  const int n0 = qt * DQT;
  const int b = bg >> 3, g = bg & 7;
  const int tid = threadIdx.x;
  const int lane = tid & 63, wave = tid >> 6;

  const float* kB = kbuf + (size_t)bg * LS * 32;
  const float* vB = vbuf + (size_t)bg * LS * 32;

  if (tid < 128) {
    const int r = tid >> 3, c4 = (tid & 7) * 4;
    *(float4*)&Qs[r][c4] =
        *(const float4*)(qb + ((size_t)(b * NQ + n0 + r)) * CM + g * DH + c4);
  }
  __syncthreads();

  float ssum[4] = {0.f, 0.f, 0.f, 0.f};

  // ---- pass 1: exp-sum only (scores provably tiny; no max subtraction) ----
#pragma unroll 1
  for (int c = 0; c < DNC; ++c) {
    {
      const int r0 = tid >> 3, c40 = (tid & 7) * 4;
      const int r1 = r0 + 32;
      *(float4*)&Ks[r0][c40] = *(const float4*)(kB + (size_t)(c * DKC + r0) * 32 + c40);
      *(float4*)&Ks[r1][c40] = *(const float4*)(kB + (size_t)(c * DKC + r1) * 32 + c40);
    }
    __syncthreads();
    float4 kr[8];
#pragma unroll
    for (int d4 = 0; d4 < 8; ++d4) kr[d4] = *(const float4*)&Ks[lane][d4 * 4];
#pragma unroll
    for (int qi = 0; qi < 4; ++qi) {
      const int q = wave * 4 + qi;
      float s = 0.f;
#pragma unroll
      for (int d4 = 0; d4 < 8; ++d4) {
        float4 q4 = *(const float4*)&Qs[q][d4 * 4];
        s += q4.x * kr[d4].x + q4.y * kr[d4].y + q4.z * kr[d4].z + q4.w * kr[d4].w;
      }
      ssum[qi] += __expf(s * 0.17677669529663687f);
    }
    __syncthreads();
  }
  float inv[4];
#pragma unroll
  for (int qi = 0; qi < 4; ++qi) {
    float ss = ssum[qi];
#pragma unroll
    for (int off = 32; off > 0; off >>= 1) ss += __shfl_xor(ss, off, 64);
    inv[qi] = 1.f / ss;
  }

  // ---- pass 2: normalized attn write + PV ----
  const int dslot = (tid >> 3) & 7;
  const int kg = tid & 7;
  float o0[4] = {}, o1[4] = {}, o2[4] = {}, o3[4] = {};

#pragma unroll 1
  for (int c = 0; c < DNC; ++c) {
    {
      const int r0 = tid >> 3, c40 = (tid & 7) * 4;
      const int r1 = r0 + 32;
      *(float4*)&Ks[r0][c40] = *(const float4*)(kB + (size_t)(c * DKC + r0) * 32 + c40);
      *(float4*)&Ks[r1][c40] = *(const float4*)(kB + (size_t)(c * DKC + r1) * 32 + c40);
      *(float4*)&Vs[r0][c40] = *(const float4*)(vB + (size_t)(c * DKC + r0) * 32 + c40);
      *(float4*)&Vs[r1][c40] = *(const float4*)(vB + (size_t)(c * DKC + r1) * 32 + c40);
    }
    __syncthreads();
    float4 kr[8];
#pragma unroll
    for (int d4 = 0; d4 < 8; ++d4) kr[d4] = *(const float4*)&Ks[lane][d4 * 4];
#pragma unroll
    for (int qi = 0; qi < 4; ++qi) {
      const int q = wave * 4 + qi;
      float s = 0.f;
#pragma unroll
      for (int d4 = 0; d4 < 8; ++d4) {
        float4 q4 = *(const float4*)&Qs[q][d4 * 4];
        s += q4.x * kr[d4].x + q4.y * kr[d4].y + q4.z * kr[d4].z + q4.w * kr[d4].w;
      }
      const float e = __expf(s * 0.17677669529663687f) * inv[qi];
      Ps[q][lane] = e;
      attn_out[((size_t)(bg * NQ + n0 + q)) * LS + c * DKC + lane] = e;
    }
    // P rows of wave w written & read by same wave -> no block barrier needed
#pragma unroll
    for (int j = 0; j < 8; ++j) {
      const int kk = kg * 8 + j;
      float4 v4 = *(const float4*)&Vs[kk][dslot * 4];
      const float p0 = Ps[wave * 4 + 0][kk];
      const float p1 = Ps[wave * 4 + 1][kk];
      const float p2 = Ps[wave * 4 + 2][kk];
      const float p3 = Ps[wave * 4 + 3][kk];
      o0[0] += p0 * v4.x; o0[1] += p0 * v4.y; o0[2] += p0 * v4.z; o0[3] += p0 * v4.w;
      o1[0] += p1 * v4.x; o1[1] += p1 * v4.y; o1[2] += p1 * v4.z; o1[3] += p1 * v4.w;
      o2[0] += p2 * v4.x; o2[1] += p2 * v4.y; o2[2] += p2 * v4.z; o2[3] += p2 * v4.w;
      o3[0] += p3 * v4.x; o3[1] += p3 * v4.y; o3[2] += p3 * v4.z; o3[3] += p3 * v4.w;
    }
    __syncthreads();
  }

#pragma unroll
  for (int j = 0; j < 4; ++j) {
    Ored[kg * (DQT * 32) + (wave * 4 + 0) * 32 + dslot * 4 + j] = o0[j];
    Ored[kg * (DQT * 32) + (wave * 4 + 1) * 32 + dslot * 4 + j] = o1[j];
    Ored[kg * (DQT * 32) + (wave * 4 + 2) * 32 + dslot * 4 + j] = o2[j];
    Ored[kg * (DQT * 32) + (wave * 4 + 3) * 32 + dslot * 4 + j] = o3[j];
  }
  __syncthreads();
#pragma unroll
  for (int i = 0; i < 2; ++i) {
    const int idx = tid * 2 + i;
    const int q = idx >> 5, d = idx & 31;
    float s = 0.f;
#pragma unroll
    for (int k = 0; k < 8; ++k) s += Ored[k * (DQT * 32) + q * 32 + d];
    da_o[((size_t)(b * NQ + n0 + q)) * CM + g * DH + d] = s;
  }
}

// ---------------- launch ----------------
extern "C" void kernel_launch(void* const* d_in, const int* in_sizes, int n_in,
                              void* d_out, int out_size, void* d_ws, size_t ws_size,
                              hipStream_t stream) {
  const float* query    = (const float*)d_in[0];
  const float* gt       = (const float*)d_in[1];
  const float* sa_in_w  = (const float*)d_in[2];
  const float* sa_in_b  = (const float*)d_in[3];
  const float* sa_out_w = (const float*)d_in[4];
  const float* sa_out_b = (const float*)d_in[5];
  const float* q_w      = (const float*)d_in[6];
  const float* off_w1   = (const float*)d_in[7];
  const float* off_b1   = (const float*)d_in[8];
  const float* off_w2   = (const float*)d_in[9];
  const float* k_w      = (const float*)d_in[10];
  const float* v_w      = (const float*)d_in[11];
  const float* da_out_w = (const float*)d_in[12];
  const float* da_out_b = (const float*)d_in[13];
  const float* lin1_w   = (const float*)d_in[14];
  const float* lin1_b   = (const float*)d_in[15];
  const float* lin2_w   = (const float*)d_in[16];
  const float* lin2_b   = (const float*)d_in[17];
  const float* ln1_w    = (const float*)d_in[18];
  const float* ln1_b    = (const float*)d_in[19];
  const float* ln2_w    = (const float*)d_in[20];
  const float* ln2_b    = (const float*)d_in[21];
  const float* ln3_w    = (const float*)d_in[22];
  const float* ln3_b    = (const float*)d_in[23];

  float* ws = (float*)d_ws;
  float* t1      = ws + 0;            // 524288
  float* t2      = ws + 524288;       // 524288
  float* off1    = ws + 1048576;      // 1048576
  float* pcoords = ws + 2097152;      // 98304
  float* k_buf   = ws + 2195456;      // 1048576
  float* v_buf   = ws + 3244032;      // 1048576
  float* q_buf   = ws + 4292608;      // 524288
  float* da_o    = ws + 4816896;      // 524288
  float* qkv_buf = ws + 5341184;      // 1572864
  float* sa_o    = ws + 6914048;      // 524288
  float* t0      = ws + 7438336;      // 524288
  float* u2      = ws + 7962624;      // 524288
  float* hbuf    = ws + 2097152;      // 4194304 (reuses pcoords/k/v/q regions, dead by then)
  float* u3      = ws + 6291456;      // 524288  (reuses qkv region)

  float* out_t    = (float*)d_out;
  float* out_attn = out_t + (size_t)MROWS * CM;

  gemm_nt<false><<<dim3(MROWS / 64, 768 / 64), 256, 0, stream>>>(
      query, sa_in_w, sa_in_b, nullptr, qkv_buf, MROWS, 768, CM);
  sa_flash_kernel<<<1024, 256, 0, stream>>>(qkv_buf, sa_o);
  gemm_nt<false><<<dim3(MROWS / 64, CM / 64), 256, 0, stream>>>(
      sa_o, sa_out_w, sa_out_b, query, t0, MROWS, CM, CM);
  ln_kernel<<<512, 256, 0, stream>>>(t0, ln1_w, ln1_b, t1);
  conv_off_kernel<<<4096, 256, 0, stream>>>(gt, off_w1, off_b1, off1);
  offproj_kernel<<<128, 256, 0, stream>>>(off1, off_w2, pcoords);
  gsample_kernel<<<4096, 256, 0, stream>>>(gt, pcoords, k_w, v_w, k_buf, v_buf);
  gemm_nt<false><<<dim3(MROWS / 64, CM / 64), 256, 0, stream>>>(
      t1, q_w, nullptr, nullptr, q_buf, MROWS, CM, CM);
  dattn_kernel<<<1024, 256, 0, stream>>>(q_buf, k_buf, v_buf, da_o, out_attn);
  gemm_nt<false><<<dim3(MROWS / 64, CM / 64), 256, 0, stream>>>(
      da_o, da_out_w, da_out_b, t1, u2, MROWS, CM, CM);
  ln_kernel<<<512, 256, 0, stream>>>(u2, ln2_w, ln2_b, t2);
  gemm_nt<true><<<dim3(MROWS / 64, FFD / 64), 256, 0, stream>>>(
      t2, lin1_w, lin1_b, nullptr, hbuf, MROWS, FFD, CM);
  gemm_nt<false><<<dim3(MROWS / 64, CM / 64), 256, 0, stream>>>(
      hbuf, lin2_w, lin2_b, t2, u3, MROWS, CM, FFD);
  ln_kernel<<<512, 256, 0, stream>>>(u3, ln3_w, ln3_b, out_t);
}

// Round 7
// 886.839 us; speedup vs baseline: 1.0011x; 1.0011x over previous
//
#include <hip/hip_runtime.h>
#include <hip/hip_bf16.h>

// ---------------- constants ----------------
#define BQ 2
#define NQ 1024
#define CM 256
#define HEADS 8
#define DH 32
#define FFD 2048
#define TV 16
#define HV 128
#define WV 128
#define TD 8
#define HD 16
#define WD 16
#define LS 2048              // TD*HD*WD samples per group
#define NG 16                // B * HEADS groups
#define MROWS 2048           // B*NQ token rows

// ---------------- generic f32 NT GEMM: C = A(MxK) @ W(NxK)^T (+bias)(+res)(+relu) ----------------
template <bool RELU>
__global__ __launch_bounds__(256) void gemm_nt(const float* __restrict__ A,
                                               const float* __restrict__ Wt,
                                               const float* __restrict__ bias,
                                               const float* __restrict__ res,
                                               float* __restrict__ C,
                                               int M, int N, int K) {
  __shared__ float As[16 * 68];
  __shared__ float Ws[16 * 68];
  const int tm = threadIdx.x & 15;
  const int tn = threadIdx.x >> 4;
  const int m0 = blockIdx.x * 64, n0 = blockIdx.y * 64;
  const int lr = threadIdx.x >> 2;
  const int lk = (threadIdx.x & 3) * 4;
  float acc[4][4] = {};
  for (int k0 = 0; k0 < K; k0 += 16) {
    float4 a4 = *(const float4*)(A + (size_t)(m0 + lr) * K + k0 + lk);
    float4 w4 = *(const float4*)(Wt + (size_t)(n0 + lr) * K + k0 + lk);
    As[(lk + 0) * 68 + lr] = a4.x;
    As[(lk + 1) * 68 + lr] = a4.y;
    As[(lk + 2) * 68 + lr] = a4.z;
    As[(lk + 3) * 68 + lr] = a4.w;
    Ws[(lk + 0) * 68 + lr] = w4.x;
    Ws[(lk + 1) * 68 + lr] = w4.y;
    Ws[(lk + 2) * 68 + lr] = w4.z;
    Ws[(lk + 3) * 68 + lr] = w4.w;
    __syncthreads();
#pragma unroll
    for (int k = 0; k < 16; ++k) {
      float4 av = *(const float4*)&As[k * 68 + tm * 4];
      float4 wv = *(const float4*)&Ws[k * 68 + tn * 4];
      float a[4] = {av.x, av.y, av.z, av.w};
      float w[4] = {wv.x, wv.y, wv.z, wv.w};
#pragma unroll
      for (int i = 0; i < 4; ++i)
#pragma unroll
        for (int j = 0; j < 4; ++j) acc[i][j] += a[i] * w[j];
    }
    __syncthreads();
  }
#pragma unroll
  for (int i = 0; i < 4; ++i) {
    const int row = m0 + tm * 4 + i;
    const int col = n0 + tn * 4;
    float4 bv = bias ? *(const float4*)(bias + col) : make_float4(0.f, 0.f, 0.f, 0.f);
    float4 rv = res ? *(const float4*)(res + (size_t)row * N + col) : make_float4(0.f, 0.f, 0.f, 0.f);
    float4 o;
    o.x = acc[i][0] + bv.x + rv.x;
    o.y = acc[i][1] + bv.y + rv.y;
    o.z = acc[i][2] + bv.z + rv.z;
    o.w = acc[i][3] + bv.w + rv.w;
    if (RELU) {
      o.x = fmaxf(o.x, 0.f); o.y = fmaxf(o.y, 0.f);
      o.z = fmaxf(o.z, 0.f); o.w = fmaxf(o.w, 0.f);
    }
    *(float4*)(C + (size_t)row * N + col) = o;
  }
}

// ---------------- self-attention: single-pass flash (scores provably tiny -> no max) ----------------
#define SKC 64
#define SNC (NQ / SKC)
__global__ __launch_bounds__(256) void sa_flash_kernel(const float* __restrict__ qkv,
                                                       float* __restrict__ o) {
  __shared__ float Qs[16][36];
  __shared__ float Ks[SKC][36];
  __shared__ float Vs[SKC][36];
  __shared__ float Ps[16][68];
  __shared__ float Ored[8 * 16 * 32];

  const int swz = (blockIdx.x & 7) * 128 + (blockIdx.x >> 3);
  const int bh = swz >> 6, qt = swz & 63;
  const int n0 = qt * 16;
  const int b = bh >> 3, h = bh & 7;
  const int tid = threadIdx.x;
  const int lane = tid & 63, wave = tid >> 6;

  const float* rowbase = qkv + (size_t)b * NQ * 768 + h * DH;

  if (tid < 128) {
    const int r = tid >> 3, c4 = (tid & 7) * 4;
    *(float4*)&Qs[r][c4] = *(const float4*)(rowbase + (size_t)(n0 + r) * 768 + c4);
  }
  __syncthreads();

  const int dslot = (tid >> 3) & 7;
  const int kg = tid & 7;
  float ssum[4] = {0.f, 0.f, 0.f, 0.f};
  float o0[4] = {}, o1[4] = {}, o2[4] = {}, o3[4] = {};

#pragma unroll 1
  for (int c = 0; c < SNC; ++c) {
    {
      const int r0 = tid >> 3, c40 = (tid & 7) * 4;
      const int r1 = r0 + 32;
      *(float4*)&Ks[r0][c40] =
          *(const float4*)(rowbase + (size_t)(c * SKC + r0) * 768 + 256 + c40);
      *(float4*)&Ks[r1][c40] =
          *(const float4*)(rowbase + (size_t)(c * SKC + r1) * 768 + 256 + c40);
      *(float4*)&Vs[r0][c40] =
          *(const float4*)(rowbase + (size_t)(c * SKC + r0) * 768 + 512 + c40);
      *(float4*)&Vs[r1][c40] =
          *(const float4*)(rowbase + (size_t)(c * SKC + r1) * 768 + 512 + c40);
    }
    __syncthreads();
    float4 kr[8];
#pragma unroll
    for (int d4 = 0; d4 < 8; ++d4) kr[d4] = *(const float4*)&Ks[lane][d4 * 4];
#pragma unroll
    for (int qi = 0; qi < 4; ++qi) {
      const int q = wave * 4 + qi;
      float s = 0.f;
#pragma unroll
      for (int d4 = 0; d4 < 8; ++d4) {
        float4 q4 = *(const float4*)&Qs[q][d4 * 4];
        s += q4.x * kr[d4].x + q4.y * kr[d4].y + q4.z * kr[d4].z + q4.w * kr[d4].w;
      }
      const float e = __expf(s * 0.17677669529663687f);
      ssum[qi] += e;
      Ps[q][lane] = e;
    }
    // P rows of wave w written & read by the same wave -> no block barrier needed
#pragma unroll
    for (int j = 0; j < 8; ++j) {
      const int kk = kg * 8 + j;
      float4 v4 = *(const float4*)&Vs[kk][dslot * 4];
      const float p0 = Ps[wave * 4 + 0][kk];
      const float p1 = Ps[wave * 4 + 1][kk];
      const float p2 = Ps[wave * 4 + 2][kk];
      const float p3 = Ps[wave * 4 + 3][kk];
      o0[0] += p0 * v4.x; o0[1] += p0 * v4.y; o0[2] += p0 * v4.z; o0[3] += p0 * v4.w;
      o1[0] += p1 * v4.x; o1[1] += p1 * v4.y; o1[2] += p1 * v4.z; o1[3] += p1 * v4.w;
      o2[0] += p2 * v4.x; o2[1] += p2 * v4.y; o2[2] += p2 * v4.z; o2[3] += p2 * v4.w;
      o3[0] += p3 * v4.x; o3[1] += p3 * v4.y; o3[2] += p3 * v4.z; o3[3] += p3 * v4.w;
    }
    __syncthreads();
  }

  float inv[4];
#pragma unroll
  for (int qi = 0; qi < 4; ++qi) {
    float ss = ssum[qi];
#pragma unroll
    for (int off = 32; off > 0; off >>= 1) ss += __shfl_xor(ss, off, 64);
    inv[qi] = 1.f / ss;
  }

#pragma unroll
  for (int j = 0; j < 4; ++j) {
    Ored[kg * (16 * 32) + (wave * 4 + 0) * 32 + dslot * 4 + j] = o0[j] * inv[0];
    Ored[kg * (16 * 32) + (wave * 4 + 1) * 32 + dslot * 4 + j] = o1[j] * inv[1];
    Ored[kg * (16 * 32) + (wave * 4 + 2) * 32 + dslot * 4 + j] = o2[j] * inv[2];
    Ored[kg * (16 * 32) + (wave * 4 + 3) * 32 + dslot * 4 + j] = o3[j] * inv[3];
  }
  __syncthreads();
#pragma unroll
  for (int i = 0; i < 2; ++i) {
    const int idx = tid * 2 + i;
    const int q = idx >> 5, d = idx & 31;
    float s = 0.f;
#pragma unroll
    for (int k = 0; k < 8; ++k) s += Ored[k * (16 * 32) + q * 32 + d];
    o[((size_t)(b * NQ + n0 + q)) * CM + h * DH + d] = s;
  }
}

// ---------------- layer norm (one wave per 256-dim row), f32 out ----------------
__global__ __launch_bounds__(256) void ln_kernel(const float* __restrict__ in,
                                                 const float* __restrict__ w,
                                                 const float* __restrict__ b,
                                                 float* __restrict__ out) {
  const int wv = threadIdx.x >> 6, lane = threadIdx.x & 63;
  const int row = blockIdx.x * 4 + wv;
  float4 v = ((const float4*)(in + (size_t)row * CM))[lane];
  float s = v.x + v.y + v.z + v.w;
#pragma unroll
  for (int off = 32; off > 0; off >>= 1) s += __shfl_xor(s, off, 64);
  const float mu = s * (1.f / 256.f);
  float dx = v.x - mu, dy = v.y - mu, dz = v.z - mu, dw = v.w - mu;
  float q = dx * dx + dy * dy + dz * dz + dw * dw;
#pragma unroll
  for (int off = 32; off > 0; off >>= 1) q += __shfl_xor(q, off, 64);
  const float r = rsqrtf(q * (1.f / 256.f) + 1e-5f);
  float4 wv4 = ((const float4*)w)[lane];
  float4 bv4 = ((const float4*)b)[lane];
  float4 o;
  o.x = dx * r * wv4.x + bv4.x;
  o.y = dy * r * wv4.y + bv4.y;
  o.z = dz * r * wv4.z + bv4.z;
  o.w = dw * r * wv4.w + bv4.w;
  ((float4*)(out + (size_t)row * CM))[lane] = o;
}

// ---------------- depthwise strided conv + bias + gelu(tanh) ----------------
// bid remapped so all 8 zo-blocks of one (bg,c) land on the SAME XCD, 8 dispatch
// slots apart -> overlapping z-planes hit that XCD's L2 instead of HBM.
__global__ __launch_bounds__(256) void conv_off_kernel(const float* __restrict__ gt,
                                                       const float* __restrict__ w1,
                                                       const float* __restrict__ b1,
                                                       float* __restrict__ off1) {
  const int bid = blockIdx.x;
  const int cid = ((bid >> 6) << 3) | (bid & 7);  // 0..511, cid%8 == bid%8
  const int zo = (bid >> 3) & 7;
  const int c = cid & 31, bg = cid >> 5;
  const int xo = threadIdx.x & 15, yo = threadIdx.x >> 4;
  __shared__ float wsm[400];
  for (int i = threadIdx.x; i < 400; i += 256) wsm[i] = w1[c * 400 + i];
  __syncthreads();
  const float* xp = gt + (size_t)(bg * 32 + c) * (TV * HV * WV);
  float acc = 0.f;
  for (int kz = 0; kz < 4; ++kz) {
    const int z = zo * 2 - 1 + kz;
    if ((unsigned)z >= (unsigned)TV) continue;
    const float* xz = xp + (size_t)z * (HV * WV);
    for (int ky = 0; ky < 10; ++ky) {
      const int y = yo * 8 - 1 + ky;
      if ((unsigned)y >= (unsigned)HV) continue;
      const float* xy = xz + y * WV;
      const float* wr = wsm + kz * 100 + ky * 10;
      const int xbase = xo * 8 - 1;
#pragma unroll
      for (int kx = 0; kx < 10; ++kx) {
        const int x = xbase + kx;
        if ((unsigned)x < (unsigned)WV) acc += wr[kx] * xy[x];
      }
    }
  }
  acc += b1[c];
  const float u = 0.7978845608028654f * (acc + 0.044715f * acc * acc * acc);
  const float gv = 0.5f * acc * (1.f + tanhf(u));
  off1[((size_t)(bg * 32 + c) * TD + zo) * (HD * WD) + yo * WD + xo] = gv;
}

// ---------------- offset projection + tanh*scale + pixel coords ----------------
__global__ __launch_bounds__(256) void offproj_kernel(const float* __restrict__ off1,
                                                      const float* __restrict__ w2,
                                                      float* __restrict__ pc) {
  const int gid = blockIdx.x * 256 + threadIdx.x;  // 16*2048
  const int bg = gid >> 11, sp = gid & 2047;
  const float* base = off1 + (size_t)bg * 32 * LS + sp;
  float o0 = 0.f, o1 = 0.f, o2 = 0.f;
#pragma unroll
  for (int c = 0; c < 32; ++c) {
    const float v = base[(size_t)c * LS];
    o0 += w2[c] * v;
    o1 += w2[32 + c] * v;
    o2 += w2[64 + c] * v;
  }
  const int gz = sp >> 8, gy = (sp >> 4) & 15, gx = sp & 15;
  const float oz = tanhf(o0) * 2.f;
  const float oy = tanhf(o1) * 8.f;
  const float ox = tanhf(o2) * 8.f;
  float* p = pc + (size_t)gid * 3;
  p[0] = ((float)gz + oz) * (16.f / 7.f) - 0.5f;
  p[1] = ((float)gy + oy) * (128.f / 15.f) - 0.5f;
  p[2] = ((float)gx + ox) * (128.f / 15.f) - 0.5f;
}

// ---------------- trilinear grid sample + per-group k/v projection ----------------
__global__ __launch_bounds__(256) void gsample_kernel(const float* __restrict__ gt,
                                                      const float* __restrict__ pc,
                                                      const float* __restrict__ kw,
                                                      const float* __restrict__ vw,
                                                      float* __restrict__ kbuf,
                                                      float* __restrict__ vbuf) {
  __shared__ float kvv[8][33];
  __shared__ float kws[32][33], vws[32][33];
  const int bg = blockIdx.x >> 8, l0 = (blockIdx.x & 255) * 8;
  const int g = bg & 7;
  const int s = threadIdx.x >> 5, c = threadIdx.x & 31;
  for (int i = threadIdx.x; i < 1024; i += 256) {
    kws[i >> 5][i & 31] = kw[g * 1024 + i];
    vws[i >> 5][i & 31] = vw[g * 1024 + i];
  }
  const int l = l0 + s;
  const float* p = pc + ((size_t)bg * LS + l) * 3;
  const float pz = p[0], py = p[1], px = p[2];
  const float zf = floorf(pz), yf = floorf(py), xf = floorf(px);
  const int z0 = (int)zf, y0 = (int)yf, x0 = (int)xf;
  const float fz = pz - zf, fy = py - yf, fx = px - xf;
  const float* vp = gt + (size_t)(bg * 32 + c) * (TV * HV * WV);
  float acc = 0.f;
#pragma unroll
  for (int dz = 0; dz < 2; ++dz) {
    const int z = z0 + dz;
    if ((unsigned)z >= (unsigned)TV) continue;
    const float wz = dz ? fz : 1.f - fz;
#pragma unroll
    for (int dy = 0; dy < 2; ++dy) {
      const int y = y0 + dy;
      if ((unsigned)y >= (unsigned)HV) continue;
      const float wzy = wz * (dy ? fy : 1.f - fy);
#pragma unroll
      for (int dx = 0; dx < 2; ++dx) {
        const int x = x0 + dx;
        if ((unsigned)x >= (unsigned)WV) continue;
        acc += wzy * (dx ? fx : 1.f - fx) * vp[((size_t)z * HV + y) * WV + x];
      }
    }
  }
  kvv[s][c] = acc;
  __syncthreads();
  float ka = 0.f, va = 0.f;
#pragma unroll
  for (int f = 0; f < 32; ++f) {
    const float kv = kvv[s][f];
    ka += kws[c][f] * kv;
    va += vws[c][f] * kv;
  }
  kbuf[((size_t)bg * LS + l) * 32 + c] = ka;
  vbuf[((size_t)bg * LS + l) * 32 + c] = va;
}

// ---------------- deformable attention: two-pass, no-max softmax ----------------
#define DQT 16
#define DKC 64
#define DNC (LS / DKC)
__global__ __launch_bounds__(256) void dattn_kernel(const float* __restrict__ qb,
                                                    const float* __restrict__ kbuf,
                                                    const float* __restrict__ vbuf,
                                                    float* __restrict__ da_o,
                                                    float* __restrict__ attn_out) {
  __shared__ float Qs[DQT][36];
  __shared__ float Ks[DKC][36];
  __shared__ float Vs[DKC][36];
  __shared__ float Ps[DQT][68];
  __shared__ float Ored[8 * DQT * 32];

  const int swz = (blockIdx.x & 7) * 128 + (blockIdx.x >> 3);
  const int bg = swz >> 6, qt = swz & 63;
  const int n0 = qt * DQT;
  const int b = bg >> 3, g = bg & 7;
  const int tid = threadIdx.x;
  const int lane = tid & 63, wave = tid >> 6;

  const float* kB = kbuf + (size_t)bg * LS * 32;
  const float* vB = vbuf + (size_t)bg * LS * 32;

  if (tid < 128) {
    const int r = tid >> 3, c4 = (tid & 7) * 4;
    *(float4*)&Qs[r][c4] =
        *(const float4*)(qb + ((size_t)(b * NQ + n0 + r)) * CM + g * DH + c4);
  }
  __syncthreads();

  float ssum[4] = {0.f, 0.f, 0.f, 0.f};

  // ---- pass 1: exp-sum only (scores provably tiny; no max subtraction) ----
#pragma unroll 1
  for (int c = 0; c < DNC; ++c) {
    {
      const int r0 = tid >> 3, c40 = (tid & 7) * 4;
      const int r1 = r0 + 32;
      *(float4*)&Ks[r0][c40] = *(const float4*)(kB + (size_t)(c * DKC + r0) * 32 + c40);
      *(float4*)&Ks[r1][c40] = *(const float4*)(kB + (size_t)(c * DKC + r1) * 32 + c40);
    }
    __syncthreads();
    float4 kr[8];
#pragma unroll
    for (int d4 = 0; d4 < 8; ++d4) kr[d4] = *(const float4*)&Ks[lane][d4 * 4];
#pragma unroll
    for (int qi = 0; qi < 4; ++qi) {
      const int q = wave * 4 + qi;
      float s = 0.f;
#pragma unroll
      for (int d4 = 0; d4 < 8; ++d4) {
        float4 q4 = *(const float4*)&Qs[q][d4 * 4];
        s += q4.x * kr[d4].x + q4.y * kr[d4].y + q4.z * kr[d4].z + q4.w * kr[d4].w;
      }
      ssum[qi] += __expf(s * 0.17677669529663687f);
    }
    __syncthreads();
  }
  float inv[4];
#pragma unroll
  for (int qi = 0; qi < 4; ++qi) {
    float ss = ssum[qi];
#pragma unroll
    for (int off = 32; off > 0; off >>= 1) ss += __shfl_xor(ss, off, 64);
    inv[qi] = 1.f / ss;
  }

  // ---- pass 2: normalized attn write + PV ----
  const int dslot = (tid >> 3) & 7;
  const int kg = tid & 7;
  float o0[4] = {}, o1[4] = {}, o2[4] = {}, o3[4] = {};

#pragma unroll 1
  for (int c = 0; c < DNC; ++c) {
    {
      const int r0 = tid >> 3, c40 = (tid & 7) * 4;
      const int r1 = r0 + 32;
      *(float4*)&Ks[r0][c40] = *(const float4*)(kB + (size_t)(c * DKC + r0) * 32 + c40);
      *(float4*)&Ks[r1][c40] = *(const float4*)(kB + (size_t)(c * DKC + r1) * 32 + c40);
      *(float4*)&Vs[r0][c40] = *(const float4*)(vB + (size_t)(c * DKC + r0) * 32 + c40);
      *(float4*)&Vs[r1][c40] = *(const float4*)(vB + (size_t)(c * DKC + r1) * 32 + c40);
    }
    __syncthreads();
    float4 kr[8];
#pragma unroll
    for (int d4 = 0; d4 < 8; ++d4) kr[d4] = *(const float4*)&Ks[lane][d4 * 4];
#pragma unroll
    for (int qi = 0; qi < 4; ++qi) {
      const int q = wave * 4 + qi;
      float s = 0.f;
#pragma unroll
      for (int d4 = 0; d4 < 8; ++d4) {
        float4 q4 = *(const float4*)&Qs[q][d4 * 4];
        s += q4.x * kr[d4].x + q4.y * kr[d4].y + q4.z * kr[d4].z + q4.w * kr[d4].w;
      }
      const float e = __expf(s * 0.17677669529663687f) * inv[qi];
      Ps[q][lane] = e;
      attn_out[((size_t)(bg * NQ + n0 + q)) * LS + c * DKC + lane] = e;
    }
    // P rows of wave w written & read by same wave -> no block barrier needed
#pragma unroll
    for (int j = 0; j < 8; ++j) {
      const int kk = kg * 8 + j;
      float4 v4 = *(const float4*)&Vs[kk][dslot * 4];
      const float p0 = Ps[wave * 4 + 0][kk];
      const float p1 = Ps[wave * 4 + 1][kk];
      const float p2 = Ps[wave * 4 + 2][kk];
      const float p3 = Ps[wave * 4 + 3][kk];
      o0[0] += p0 * v4.x; o0[1] += p0 * v4.y; o0[2] += p0 * v4.z; o0[3] += p0 * v4.w;
      o1[0] += p1 * v4.x; o1[1] += p1 * v4.y; o1[2] += p1 * v4.z; o1[3] += p1 * v4.w;
      o2[0] += p2 * v4.x; o2[1] += p2 * v4.y; o2[2] += p2 * v4.z; o2[3] += p2 * v4.w;
      o3[0] += p3 * v4.x; o3[1] += p3 * v4.y; o3[2] += p3 * v4.z; o3[3] += p3 * v4.w;
    }
    __syncthreads();
  }

#pragma unroll
  for (int j = 0; j < 4; ++j) {
    Ored[kg * (DQT * 32) + (wave * 4 + 0) * 32 + dslot * 4 + j] = o0[j];
    Ored[kg * (DQT * 32) + (wave * 4 + 1) * 32 + dslot * 4 + j] = o1[j];
    Ored[kg * (DQT * 32) + (wave * 4 + 2) * 32 + dslot * 4 + j] = o2[j];
    Ored[kg * (DQT * 32) + (wave * 4 + 3) * 32 + dslot * 4 + j] = o3[j];
  }
  __syncthreads();
#pragma unroll
  for (int i = 0; i < 2; ++i) {
    const int idx = tid * 2 + i;
    const int q = idx >> 5, d = idx & 31;
    float s = 0.f;
#pragma unroll
    for (int k = 0; k < 8; ++k) s += Ored[k * (DQT * 32) + q * 32 + d];
    da_o[((size_t)(b * NQ + n0 + q)) * CM + g * DH + d] = s;
  }
}

// ---------------- launch ----------------
extern "C" void kernel_launch(void* const* d_in, const int* in_sizes, int n_in,
                              void* d_out, int out_size, void* d_ws, size_t ws_size,
                              hipStream_t stream) {
  const float* query    = (const float*)d_in[0];
  const float* gt       = (const float*)d_in[1];
  const float* sa_in_w  = (const float*)d_in[2];
  const float* sa_in_b  = (const float*)d_in[3];
  const float* sa_out_w = (const float*)d_in[4];
  const float* sa_out_b = (const float*)d_in[5];
  const float* q_w      = (const float*)d_in[6];
  const float* off_w1   = (const float*)d_in[7];
  const float* off_b1   = (const float*)d_in[8];
  const float* off_w2   = (const float*)d_in[9];
  const float* k_w      = (const float*)d_in[10];
  const float* v_w      = (const float*)d_in[11];
  const float* da_out_w = (const float*)d_in[12];
  const float* da_out_b = (const float*)d_in[13];
  const float* lin1_w   = (const float*)d_in[14];
  const float* lin1_b   = (const float*)d_in[15];
  const float* lin2_w   = (const float*)d_in[16];
  const float* lin2_b   = (const float*)d_in[17];
  const float* ln1_w    = (const float*)d_in[18];
  const float* ln1_b    = (const float*)d_in[19];
  const float* ln2_w    = (const float*)d_in[20];
  const float* ln2_b    = (const float*)d_in[21];
  const float* ln3_w    = (const float*)d_in[22];
  const float* ln3_b    = (const float*)d_in[23];

  float* ws = (float*)d_ws;
  float* t1      = ws + 0;            // 524288
  float* t2      = ws + 524288;       // 524288
  float* off1    = ws + 1048576;      // 1048576
  float* pcoords = ws + 2097152;      // 98304
  float* k_buf   = ws + 2195456;      // 1048576
  float* v_buf   = ws + 3244032;      // 1048576
  float* q_buf   = ws + 4292608;      // 524288
  float* da_o    = ws + 4816896;      // 524288
  float* qkv_buf = ws + 5341184;      // 1572864
  float* sa_o    = ws + 6914048;      // 524288
  float* t0      = ws + 7438336;      // 524288
  float* u2      = ws + 7962624;      // 524288
  float* hbuf    = ws + 2097152;      // 4194304 (reuses pcoords/k/v/q regions, dead by then)
  float* u3      = ws + 6291456;      // 524288  (reuses qkv region)

  float* out_t    = (float*)d_out;
  float* out_attn = out_t + (size_t)MROWS * CM;

  gemm_nt<false><<<dim3(MROWS / 64, 768 / 64), 256, 0, stream>>>(
      query, sa_in_w, sa_in_b, nullptr, qkv_buf, MROWS, 768, CM);
  sa_flash_kernel<<<1024, 256, 0, stream>>>(qkv_buf, sa_o);
  gemm_nt<false><<<dim3(MROWS / 64, CM / 64), 256, 0, stream>>>(
      sa_o, sa_out_w, sa_out_b, query, t0, MROWS, CM, CM);
  ln_kernel<<<512, 256, 0, stream>>>(t0, ln1_w, ln1_b, t1);
  conv_off_kernel<<<4096, 256, 0, stream>>>(gt, off_w1, off_b1, off1);
  offproj_kernel<<<128, 256, 0, stream>>>(off1, off_w2, pcoords);
  gsample_kernel<<<4096, 256, 0, stream>>>(gt, pcoords, k_w, v_w, k_buf, v_buf);
  gemm_nt<false><<<dim3(MROWS / 64, CM / 64), 256, 0, stream>>>(
      t1, q_w, nullptr, nullptr, q_buf, MROWS, CM, CM);
  dattn_kernel<<<1024, 256, 0, stream>>>(q_buf, k_buf, v_buf, da_o, out_attn);
  gemm_nt<false><<<dim3(MROWS / 64, CM / 64), 256, 0, stream>>>(
      da_o, da_out_w, da_out_b, t1, u2, MROWS, CM, CM);
  ln_kernel<<<512, 256, 0, stream>>>(u2, ln2_w, ln2_b, t2);
  gemm_nt<true><<<dim3(MROWS / 64, FFD / 64), 256, 0, stream>>>(
      t2, lin1_w, lin1_b, nullptr, hbuf, MROWS, FFD, CM);
  gemm_nt<false><<<dim3(MROWS / 64, CM / 64), 256, 0, stream>>>(
      hbuf, lin2_w, lin2_b, t2, u3, MROWS, CM, FFD);
  ln_kernel<<<512, 256, 0, stream>>>(u3, ln3_w, ln3_b, out_t);
}

// Round 8
// 754.150 us; speedup vs baseline: 1.1772x; 1.1759x over previous
//
#include <hip/hip_runtime.h>
#include <hip/hip_bf16.h>

// ---------------- constants ----------------
#define BQ 2
#define NQ 1024
#define CM 256
#define HEADS 8
#define DH 32
#define FFD 2048
#define TV 16
#define HV 128
#define WV 128
#define TD 8
#define HD 16
#define WD 16
#define LS 2048              // TD*HD*WD samples per group
#define NG 16                // B * HEADS groups
#define MROWS 2048           // B*NQ token rows

// ---------------- generic f32 NT GEMM: C = A(MxK) @ W(NxK)^T (+bias)(+res)(+relu) ----------------
template <bool RELU>
__global__ __launch_bounds__(256) void gemm_nt(const float* __restrict__ A,
                                               const float* __restrict__ Wt,
                                               const float* __restrict__ bias,
                                               const float* __restrict__ res,
                                               float* __restrict__ C,
                                               int M, int N, int K) {
  __shared__ float As[16 * 68];
  __shared__ float Ws[16 * 68];
  const int tm = threadIdx.x & 15;
  const int tn = threadIdx.x >> 4;
  const int m0 = blockIdx.x * 64, n0 = blockIdx.y * 64;
  const int lr = threadIdx.x >> 2;
  const int lk = (threadIdx.x & 3) * 4;
  float acc[4][4] = {};
  for (int k0 = 0; k0 < K; k0 += 16) {
    float4 a4 = *(const float4*)(A + (size_t)(m0 + lr) * K + k0 + lk);
    float4 w4 = *(const float4*)(Wt + (size_t)(n0 + lr) * K + k0 + lk);
    As[(lk + 0) * 68 + lr] = a4.x;
    As[(lk + 1) * 68 + lr] = a4.y;
    As[(lk + 2) * 68 + lr] = a4.z;
    As[(lk + 3) * 68 + lr] = a4.w;
    Ws[(lk + 0) * 68 + lr] = w4.x;
    Ws[(lk + 1) * 68 + lr] = w4.y;
    Ws[(lk + 2) * 68 + lr] = w4.z;
    Ws[(lk + 3) * 68 + lr] = w4.w;
    __syncthreads();
#pragma unroll
    for (int k = 0; k < 16; ++k) {
      float4 av = *(const float4*)&As[k * 68 + tm * 4];
      float4 wv = *(const float4*)&Ws[k * 68 + tn * 4];
      float a[4] = {av.x, av.y, av.z, av.w};
      float w[4] = {wv.x, wv.y, wv.z, wv.w};
#pragma unroll
      for (int i = 0; i < 4; ++i)
#pragma unroll
        for (int j = 0; j < 4; ++j) acc[i][j] += a[i] * w[j];
    }
    __syncthreads();
  }
#pragma unroll
  for (int i = 0; i < 4; ++i) {
    const int row = m0 + tm * 4 + i;
    const int col = n0 + tn * 4;
    float4 bv = bias ? *(const float4*)(bias + col) : make_float4(0.f, 0.f, 0.f, 0.f);
    float4 rv = res ? *(const float4*)(res + (size_t)row * N + col) : make_float4(0.f, 0.f, 0.f, 0.f);
    float4 o;
    o.x = acc[i][0] + bv.x + rv.x;
    o.y = acc[i][1] + bv.y + rv.y;
    o.z = acc[i][2] + bv.z + rv.z;
    o.w = acc[i][3] + bv.w + rv.w;
    if (RELU) {
      o.x = fmaxf(o.x, 0.f); o.y = fmaxf(o.y, 0.f);
      o.z = fmaxf(o.z, 0.f); o.w = fmaxf(o.w, 0.f);
    }
    *(float4*)(C + (size_t)row * N + col) = o;
  }
}

// ---------------- self-attention: single-pass flash (scores provably tiny -> no max) ----------------
#define SKC 64
#define SNC (NQ / SKC)
__global__ __launch_bounds__(256) void sa_flash_kernel(const float* __restrict__ qkv,
                                                       float* __restrict__ o) {
  __shared__ float Qs[16][36];
  __shared__ float Ks[SKC][36];
  __shared__ float Vs[SKC][36];
  __shared__ float Ps[16][68];
  __shared__ float Ored[8 * 16 * 32];

  const int swz = (blockIdx.x & 7) * 128 + (blockIdx.x >> 3);
  const int bh = swz >> 6, qt = swz & 63;
  const int n0 = qt * 16;
  const int b = bh >> 3, h = bh & 7;
  const int tid = threadIdx.x;
  const int lane = tid & 63, wave = tid >> 6;

  const float* rowbase = qkv + (size_t)b * NQ * 768 + h * DH;

  if (tid < 128) {
    const int r = tid >> 3, c4 = (tid & 7) * 4;
    *(float4*)&Qs[r][c4] = *(const float4*)(rowbase + (size_t)(n0 + r) * 768 + c4);
  }
  __syncthreads();

  const int dslot = (tid >> 3) & 7;
  const int kg = tid & 7;
  float ssum[4] = {0.f, 0.f, 0.f, 0.f};
  float o0[4] = {}, o1[4] = {}, o2[4] = {}, o3[4] = {};

#pragma unroll 1
  for (int c = 0; c < SNC; ++c) {
    {
      const int r0 = tid >> 3, c40 = (tid & 7) * 4;
      const int r1 = r0 + 32;
      *(float4*)&Ks[r0][c40] =
          *(const float4*)(rowbase + (size_t)(c * SKC + r0) * 768 + 256 + c40);
      *(float4*)&Ks[r1][c40] =
          *(const float4*)(rowbase + (size_t)(c * SKC + r1) * 768 + 256 + c40);
      *(float4*)&Vs[r0][c40] =
          *(const float4*)(rowbase + (size_t)(c * SKC + r0) * 768 + 512 + c40);
      *(float4*)&Vs[r1][c40] =
          *(const float4*)(rowbase + (size_t)(c * SKC + r1) * 768 + 512 + c40);
    }
    __syncthreads();
    float4 kr[8];
#pragma unroll
    for (int d4 = 0; d4 < 8; ++d4) kr[d4] = *(const float4*)&Ks[lane][d4 * 4];
#pragma unroll
    for (int qi = 0; qi < 4; ++qi) {
      const int q = wave * 4 + qi;
      float s = 0.f;
#pragma unroll
      for (int d4 = 0; d4 < 8; ++d4) {
        float4 q4 = *(const float4*)&Qs[q][d4 * 4];
        s += q4.x * kr[d4].x + q4.y * kr[d4].y + q4.z * kr[d4].z + q4.w * kr[d4].w;
      }
      const float e = __expf(s * 0.17677669529663687f);
      ssum[qi] += e;
      Ps[q][lane] = e;
    }
    // P rows of wave w written & read by the same wave -> no block barrier needed
#pragma unroll
    for (int j = 0; j < 8; ++j) {
      const int kk = kg * 8 + j;
      float4 v4 = *(const float4*)&Vs[kk][dslot * 4];
      const float p0 = Ps[wave * 4 + 0][kk];
      const float p1 = Ps[wave * 4 + 1][kk];
      const float p2 = Ps[wave * 4 + 2][kk];
      const float p3 = Ps[wave * 4 + 3][kk];
      o0[0] += p0 * v4.x; o0[1] += p0 * v4.y; o0[2] += p0 * v4.z; o0[3] += p0 * v4.w;
      o1[0] += p1 * v4.x; o1[1] += p1 * v4.y; o1[2] += p1 * v4.z; o1[3] += p1 * v4.w;
      o2[0] += p2 * v4.x; o2[1] += p2 * v4.y; o2[2] += p2 * v4.z; o2[3] += p2 * v4.w;
      o3[0] += p3 * v4.x; o3[1] += p3 * v4.y; o3[2] += p3 * v4.z; o3[3] += p3 * v4.w;
    }
    __syncthreads();
  }

  float inv[4];
#pragma unroll
  for (int qi = 0; qi < 4; ++qi) {
    float ss = ssum[qi];
#pragma unroll
    for (int off = 32; off > 0; off >>= 1) ss += __shfl_xor(ss, off, 64);
    inv[qi] = 1.f / ss;
  }

#pragma unroll
  for (int j = 0; j < 4; ++j) {
    Ored[kg * (16 * 32) + (wave * 4 + 0) * 32 + dslot * 4 + j] = o0[j] * inv[0];
    Ored[kg * (16 * 32) + (wave * 4 + 1) * 32 + dslot * 4 + j] = o1[j] * inv[1];
    Ored[kg * (16 * 32) + (wave * 4 + 2) * 32 + dslot * 4 + j] = o2[j] * inv[2];
    Ored[kg * (16 * 32) + (wave * 4 + 3) * 32 + dslot * 4 + j] = o3[j] * inv[3];
  }
  __syncthreads();
#pragma unroll
  for (int i = 0; i < 2; ++i) {
    const int idx = tid * 2 + i;
    const int q = idx >> 5, d = idx & 31;
    float s = 0.f;
#pragma unroll
    for (int k = 0; k < 8; ++k) s += Ored[k * (16 * 32) + q * 32 + d];
    o[((size_t)(b * NQ + n0 + q)) * CM + h * DH + d] = s;
  }
}

// ---------------- layer norm (one wave per 256-dim row), f32 out ----------------
__global__ __launch_bounds__(256) void ln_kernel(const float* __restrict__ in,
                                                 const float* __restrict__ w,
                                                 const float* __restrict__ b,
                                                 float* __restrict__ out) {
  const int wv = threadIdx.x >> 6, lane = threadIdx.x & 63;
  const int row = blockIdx.x * 4 + wv;
  float4 v = ((const float4*)(in + (size_t)row * CM))[lane];
  float s = v.x + v.y + v.z + v.w;
#pragma unroll
  for (int off = 32; off > 0; off >>= 1) s += __shfl_xor(s, off, 64);
  const float mu = s * (1.f / 256.f);
  float dx = v.x - mu, dy = v.y - mu, dz = v.z - mu, dw = v.w - mu;
  float q = dx * dx + dy * dy + dz * dz + dw * dw;
#pragma unroll
  for (int off = 32; off > 0; off >>= 1) q += __shfl_xor(q, off, 64);
  const float r = rsqrtf(q * (1.f / 256.f) + 1e-5f);
  float4 wv4 = ((const float4*)w)[lane];
  float4 bv4 = ((const float4*)b)[lane];
  float4 o;
  o.x = dx * r * wv4.x + bv4.x;
  o.y = dy * r * wv4.y + bv4.y;
  o.z = dz * r * wv4.z + bv4.z;
  o.w = dw * r * wv4.w + bv4.w;
  ((float4*)(out + (size_t)row * CM))[lane] = o;
}

// ---------------- depthwise strided conv v2: all-zo-per-thread, float2 windows ----------------
// block = (bg*32+c, zhalf): 1024 blocks. thread (xo,yo) computes 4 zo outputs.
// Each z-plane window is loaded ONCE and feeds the (up to) 2 zo's it contributes to.
__global__ __launch_bounds__(256) void conv_off2_kernel(const float* __restrict__ gt,
                                                        const float* __restrict__ w1,
                                                        const float* __restrict__ b1,
                                                        float* __restrict__ off1) {
  const int bid = blockIdx.x;
  const int zh = bid & 1, cid = bid >> 1;      // cid = bg*32+c
  const int c = cid & 31;
  const int xo = threadIdx.x & 15, yo = threadIdx.x >> 4;
  const float* __restrict__ xp = gt + (size_t)cid * (TV * HV * WV);
  const float* __restrict__ wc = w1 + c * 400;
  float acc[4] = {0.f, 0.f, 0.f, 0.f};
  const int xb = xo * 8 - 2;

#pragma unroll
  for (int zz = 0; zz < 10; ++zz) {
    const int z = 8 * zh - 1 + zz;
    if (z < 0 || z > 15) continue;             // block-uniform branch
    // compile-time acc indices: idxA = zz>>1 (kz = zz&1), idxB = idxA-1 (kz = (zz&1)+2)
    const int idxA = zz >> 1;
    const int idxB = idxA - 1;
    const int kzA = zz & 1;
    const int kzB = kzA + 2;
    const float* __restrict__ xz = xp + (size_t)z * (HV * WV);
#pragma unroll 1
    for (int ky = 0; ky < 10; ++ky) {
      const int y = yo * 8 - 1 + ky;
      if ((unsigned)y >= (unsigned)HV) continue;
      const float* __restrict__ row = xz + y * WV;
      float v[12];
#pragma unroll
      for (int j = 0; j < 6; ++j) {
        const int x = xb + 2 * j;
        if ((unsigned)x <= 126u) {
          float2 t = *(const float2*)(row + x);
          v[2 * j] = t.x; v[2 * j + 1] = t.y;
        } else {
          v[2 * j] = 0.f; v[2 * j + 1] = 0.f;
        }
      }
      if (idxA < 4) {                          // compile-time
        const float* __restrict__ wr = wc + kzA * 100 + ky * 10;
        float s = wr[0] * v[1] + wr[1] * v[2] + wr[2] * v[3] + wr[3] * v[4] +
                  wr[4] * v[5] + wr[5] * v[6] + wr[6] * v[7] + wr[7] * v[8] +
                  wr[8] * v[9] + wr[9] * v[10];
        acc[idxA & 3] += s;
      }
      if (idxB >= 0) {                         // compile-time
        const float* __restrict__ wr = wc + kzB * 100 + ky * 10;
        float s = wr[0] * v[1] + wr[1] * v[2] + wr[2] * v[3] + wr[3] * v[4] +
                  wr[4] * v[5] + wr[5] * v[6] + wr[6] * v[7] + wr[7] * v[8] +
                  wr[8] * v[9] + wr[9] * v[10];
        acc[idxB & 3] += s;
      }
    }
  }

  const float bias = b1[c];
#pragma unroll
  for (int i = 0; i < 4; ++i) {
    const int zo = zh * 4 + i;
    float a = acc[i] + bias;
    const float u = 0.7978845608028654f * (a + 0.044715f * a * a * a);
    const float gv = 0.5f * a * (1.f + tanhf(u));
    off1[((size_t)cid * TD + zo) * (HD * WD) + yo * WD + xo] = gv;
  }
}

// ---------------- offset projection + tanh*scale + pixel coords ----------------
__global__ __launch_bounds__(256) void offproj_kernel(const float* __restrict__ off1,
                                                      const float* __restrict__ w2,
                                                      float* __restrict__ pc) {
  const int gid = blockIdx.x * 256 + threadIdx.x;  // 16*2048
  const int bg = gid >> 11, sp = gid & 2047;
  const float* base = off1 + (size_t)bg * 32 * LS + sp;
  float o0 = 0.f, o1 = 0.f, o2 = 0.f;
#pragma unroll
  for (int c = 0; c < 32; ++c) {
    const float v = base[(size_t)c * LS];
    o0 += w2[c] * v;
    o1 += w2[32 + c] * v;
    o2 += w2[64 + c] * v;
  }
  const int gz = sp >> 8, gy = (sp >> 4) & 15, gx = sp & 15;
  const float oz = tanhf(o0) * 2.f;
  const float oy = tanhf(o1) * 8.f;
  const float ox = tanhf(o2) * 8.f;
  float* p = pc + (size_t)gid * 3;
  p[0] = ((float)gz + oz) * (16.f / 7.f) - 0.5f;
  p[1] = ((float)gy + oy) * (128.f / 15.f) - 0.5f;
  p[2] = ((float)gx + ox) * (128.f / 15.f) - 0.5f;
}

// ---------------- trilinear grid sample + per-group k/v projection ----------------
// XCD-chunked: each XCD owns 2 bgs and walks l (z-major) in order -> z-slab L2 locality.
__global__ __launch_bounds__(256) void gsample_kernel(const float* __restrict__ gt,
                                                      const float* __restrict__ pc,
                                                      const float* __restrict__ kw,
                                                      const float* __restrict__ vw,
                                                      float* __restrict__ kbuf,
                                                      float* __restrict__ vbuf) {
  __shared__ float kvv[8][33];
  __shared__ float kws[32][33], vws[32][33];
  const int swz = (blockIdx.x & 7) * 512 + (blockIdx.x >> 3);
  const int bg = swz >> 8, l0 = (swz & 255) * 8;
  const int g = bg & 7;
  const int s = threadIdx.x >> 5, c = threadIdx.x & 31;
  for (int i = threadIdx.x; i < 1024; i += 256) {
    kws[i >> 5][i & 31] = kw[g * 1024 + i];
    vws[i >> 5][i & 31] = vw[g * 1024 + i];
  }
  const int l = l0 + s;
  const float* p = pc + ((size_t)bg * LS + l) * 3;
  const float pz = p[0], py = p[1], px = p[2];
  const float zf = floorf(pz), yf = floorf(py), xf = floorf(px);
  const int z0 = (int)zf, y0 = (int)yf, x0 = (int)xf;
  const float fz = pz - zf, fy = py - yf, fx = px - xf;
  const float* vp = gt + (size_t)(bg * 32 + c) * (TV * HV * WV);
  float acc = 0.f;
#pragma unroll
  for (int dz = 0; dz < 2; ++dz) {
    const int z = z0 + dz;
    if ((unsigned)z >= (unsigned)TV) continue;
    const float wz = dz ? fz : 1.f - fz;
#pragma unroll
    for (int dy = 0; dy < 2; ++dy) {
      const int y = y0 + dy;
      if ((unsigned)y >= (unsigned)HV) continue;
      const float wzy = wz * (dy ? fy : 1.f - fy);
#pragma unroll
      for (int dx = 0; dx < 2; ++dx) {
        const int x = x0 + dx;
        if ((unsigned)x >= (unsigned)WV) continue;
        acc += wzy * (dx ? fx : 1.f - fx) * vp[((size_t)z * HV + y) * WV + x];
      }
    }
  }
  kvv[s][c] = acc;
  __syncthreads();
  float ka = 0.f, va = 0.f;
#pragma unroll
  for (int f = 0; f < 32; ++f) {
    const float kv = kvv[s][f];
    ka += kws[c][f] * kv;
    va += vws[c][f] * kv;
  }
  kbuf[((size_t)bg * LS + l) * 32 + c] = ka;
  vbuf[((size_t)bg * LS + l) * 32 + c] = va;
}

// ---------------- deformable attention: SINGLE pass; attn written unnormalized ----------------
#define DQT 16
#define DKC 64
#define DNC (LS / DKC)
__global__ __launch_bounds__(256) void dattn_kernel(const float* __restrict__ qb,
                                                    const float* __restrict__ kbuf,
                                                    const float* __restrict__ vbuf,
                                                    float* __restrict__ da_o,
                                                    float* __restrict__ attn_out,
                                                    float* __restrict__ invb) {
  __shared__ float Qs[DQT][36];
  __shared__ float Ks[DKC][36];
  __shared__ float Vs[DKC][36];
  __shared__ float Ps[DQT][68];
  __shared__ float Ored[8 * DQT * 32];

  const int swz = (blockIdx.x & 7) * 128 + (blockIdx.x >> 3);
  const int bg = swz >> 6, qt = swz & 63;
  const int n0 = qt * DQT;
  const int b = bg >> 3, g = bg & 7;
  const int tid = threadIdx.x;
  const int lane = tid & 63, wave = tid >> 6;

  const float* kB = kbuf + (size_t)bg * LS * 32;
  const float* vB = vbuf + (size_t)bg * LS * 32;

  if (tid < 128) {
    const int r = tid >> 3, c4 = (tid & 7) * 4;
    *(float4*)&Qs[r][c4] =
        *(const float4*)(qb + ((size_t)(b * NQ + n0 + r)) * CM + g * DH + c4);
  }
  __syncthreads();

  const int dslot = (tid >> 3) & 7;
  const int kg = tid & 7;
  float ssum[4] = {0.f, 0.f, 0.f, 0.f};
  float o0[4] = {}, o1[4] = {}, o2[4] = {}, o3[4] = {};

#pragma unroll 1
  for (int c = 0; c < DNC; ++c) {
    {
      const int r0 = tid >> 3, c40 = (tid & 7) * 4;
      const int r1 = r0 + 32;
      *(float4*)&Ks[r0][c40] = *(const float4*)(kB + (size_t)(c * DKC + r0) * 32 + c40);
      *(float4*)&Ks[r1][c40] = *(const float4*)(kB + (size_t)(c * DKC + r1) * 32 + c40);
      *(float4*)&Vs[r0][c40] = *(const float4*)(vB + (size_t)(c * DKC + r0) * 32 + c40);
      *(float4*)&Vs[r1][c40] = *(const float4*)(vB + (size_t)(c * DKC + r1) * 32 + c40);
    }
    __syncthreads();
    float4 kr[8];
#pragma unroll
    for (int d4 = 0; d4 < 8; ++d4) kr[d4] = *(const float4*)&Ks[lane][d4 * 4];
#pragma unroll
    for (int qi = 0; qi < 4; ++qi) {
      const int q = wave * 4 + qi;
      float s = 0.f;
#pragma unroll
      for (int d4 = 0; d4 < 8; ++d4) {
        float4 q4 = *(const float4*)&Qs[q][d4 * 4];
        s += q4.x * kr[d4].x + q4.y * kr[d4].y + q4.z * kr[d4].z + q4.w * kr[d4].w;
      }
      const float e = __expf(s * 0.17677669529663687f);
      ssum[qi] += e;
      Ps[q][lane] = e;
      attn_out[((size_t)(bg * NQ + n0 + q)) * LS + c * DKC + lane] = e;  // unnormalized
    }
    // P rows of wave w written & read by same wave -> no block barrier needed
#pragma unroll
    for (int j = 0; j < 8; ++j) {
      const int kk = kg * 8 + j;
      float4 v4 = *(const float4*)&Vs[kk][dslot * 4];
      const float p0 = Ps[wave * 4 + 0][kk];
      const float p1 = Ps[wave * 4 + 1][kk];
      const float p2 = Ps[wave * 4 + 2][kk];
      const float p3 = Ps[wave * 4 + 3][kk];
      o0[0] += p0 * v4.x; o0[1] += p0 * v4.y; o0[2] += p0 * v4.z; o0[3] += p0 * v4.w;
      o1[0] += p1 * v4.x; o1[1] += p1 * v4.y; o1[2] += p1 * v4.z; o1[3] += p1 * v4.w;
      o2[0] += p2 * v4.x; o2[1] += p2 * v4.y; o2[2] += p2 * v4.z; o2[3] += p2 * v4.w;
      o3[0] += p3 * v4.x; o3[1] += p3 * v4.y; o3[2] += p3 * v4.z; o3[3] += p3 * v4.w;
    }
    __syncthreads();
  }

  float inv[4];
#pragma unroll
  for (int qi = 0; qi < 4; ++qi) {
    float ss = ssum[qi];
#pragma unroll
    for (int off = 32; off > 0; off >>= 1) ss += __shfl_xor(ss, off, 64);
    inv[qi] = 1.f / ss;
  }
  if (lane == 0) {
#pragma unroll
    for (int qi = 0; qi < 4; ++qi)
      invb[(size_t)bg * NQ + n0 + wave * 4 + qi] = inv[qi];
  }

#pragma unroll
  for (int j = 0; j < 4; ++j) {
    Ored[kg * (DQT * 32) + (wave * 4 + 0) * 32 + dslot * 4 + j] = o0[j] * inv[0];
    Ored[kg * (DQT * 32) + (wave * 4 + 1) * 32 + dslot * 4 + j] = o1[j] * inv[1];
    Ored[kg * (DQT * 32) + (wave * 4 + 2) * 32 + dslot * 4 + j] = o2[j] * inv[2];
    Ored[kg * (DQT * 32) + (wave * 4 + 3) * 32 + dslot * 4 + j] = o3[j] * inv[3];
  }
  __syncthreads();
#pragma unroll
  for (int i = 0; i < 2; ++i) {
    const int idx = tid * 2 + i;
    const int q = idx >> 5, d = idx & 31;
    float s = 0.f;
#pragma unroll
    for (int k = 0; k < 8; ++k) s += Ored[k * (DQT * 32) + q * 32 + d];
    da_o[((size_t)(b * NQ + n0 + q)) * CM + g * DH + d] = s;
  }
}

// ---------------- attn normalization: one block per (bg,n) row ----------------
__global__ __launch_bounds__(256) void attn_scale_kernel(float* __restrict__ attn,
                                                         const float* __restrict__ invb) {
  const int row = blockIdx.x;
  const float inv = invb[row];
  float4* p = (float4*)(attn + (size_t)row * LS);
  const int t = threadIdx.x;
  float4 a = p[t], b = p[t + 256];
  a.x *= inv; a.y *= inv; a.z *= inv; a.w *= inv;
  b.x *= inv; b.y *= inv; b.z *= inv; b.w *= inv;
  p[t] = a;
  p[t + 256] = b;
}

// ---------------- launch ----------------
extern "C" void kernel_launch(void* const* d_in, const int* in_sizes, int n_in,
                              void* d_out, int out_size, void* d_ws, size_t ws_size,
                              hipStream_t stream) {
  const float* query    = (const float*)d_in[0];
  const float* gt       = (const float*)d_in[1];
  const float* sa_in_w  = (const float*)d_in[2];
  const float* sa_in_b  = (const float*)d_in[3];
  const float* sa_out_w = (const float*)d_in[4];
  const float* sa_out_b = (const float*)d_in[5];
  const float* q_w      = (const float*)d_in[6];
  const float* off_w1   = (const float*)d_in[7];
  const float* off_b1   = (const float*)d_in[8];
  const float* off_w2   = (const float*)d_in[9];
  const float* k_w      = (const float*)d_in[10];
  const float* v_w      = (const float*)d_in[11];
  const float* da_out_w = (const float*)d_in[12];
  const float* da_out_b = (const float*)d_in[13];
  const float* lin1_w   = (const float*)d_in[14];
  const float* lin1_b   = (const float*)d_in[15];
  const float* lin2_w   = (const float*)d_in[16];
  const float* lin2_b   = (const float*)d_in[17];
  const float* ln1_w    = (const float*)d_in[18];
  const float* ln1_b    = (const float*)d_in[19];
  const float* ln2_w    = (const float*)d_in[20];
  const float* ln2_b    = (const float*)d_in[21];
  const float* ln3_w    = (const float*)d_in[22];
  const float* ln3_b    = (const float*)d_in[23];

  float* ws = (float*)d_ws;
  float* t1      = ws + 0;            // 524288
  float* t2      = ws + 524288;       // 524288
  float* off1    = ws + 1048576;      // 1048576
  float* pcoords = ws + 2097152;      // 98304
  float* k_buf   = ws + 2195456;      // 1048576
  float* v_buf   = ws + 3244032;      // 1048576
  float* q_buf   = ws + 4292608;      // 524288
  float* da_o    = ws + 4816896;      // 524288
  float* qkv_buf = ws + 5341184;      // 1572864
  float* sa_o    = ws + 6914048;      // 524288
  float* t0      = ws + 7438336;      // 524288
  float* u2      = ws + 7962624;      // 524288
  float* inv_buf = ws + 8486912;      // 16384
  float* hbuf    = ws + 2097152;      // 4194304 (reuses pcoords/k/v/q regions, dead by then)
  float* u3      = ws + 6291456;      // 524288  (reuses qkv region)

  float* out_t    = (float*)d_out;
  float* out_attn = out_t + (size_t)MROWS * CM;

  gemm_nt<false><<<dim3(MROWS / 64, 768 / 64), 256, 0, stream>>>(
      query, sa_in_w, sa_in_b, nullptr, qkv_buf, MROWS, 768, CM);
  sa_flash_kernel<<<1024, 256, 0, stream>>>(qkv_buf, sa_o);
  gemm_nt<false><<<dim3(MROWS / 64, CM / 64), 256, 0, stream>>>(
      sa_o, sa_out_w, sa_out_b, query, t0, MROWS, CM, CM);
  ln_kernel<<<512, 256, 0, stream>>>(t0, ln1_w, ln1_b, t1);
  conv_off2_kernel<<<1024, 256, 0, stream>>>(gt, off_w1, off_b1, off1);
  offproj_kernel<<<128, 256, 0, stream>>>(off1, off_w2, pcoords);
  gsample_kernel<<<4096, 256, 0, stream>>>(gt, pcoords, k_w, v_w, k_buf, v_buf);
  gemm_nt<false><<<dim3(MROWS / 64, CM / 64), 256, 0, stream>>>(
      t1, q_w, nullptr, nullptr, q_buf, MROWS, CM, CM);
  dattn_kernel<<<1024, 256, 0, stream>>>(q_buf, k_buf, v_buf, da_o, out_attn, inv_buf);
  attn_scale_kernel<<<16384, 256, 0, stream>>>(out_attn, inv_buf);
  gemm_nt<false><<<dim3(MROWS / 64, CM / 64), 256, 0, stream>>>(
      da_o, da_out_w, da_out_b, t1, u2, MROWS, CM, CM);
  ln_kernel<<<512, 256, 0, stream>>>(u2, ln2_w, ln2_b, t2);
  gemm_nt<true><<<dim3(MROWS / 64, FFD / 64), 256, 0, stream>>>(
      t2, lin1_w, lin1_b, nullptr, hbuf, MROWS, FFD, CM);
  gemm_nt<false><<<dim3(MROWS / 64, CM / 64), 256, 0, stream>>>(
      hbuf, lin2_w, lin2_b, t2, u3, MROWS, CM, FFD);
  ln_kernel<<<512, 256, 0, stream>>>(u3, ln3_w, ln3_b, out_t);
}